// Round 12
// baseline (72.575 us; speedup 1.0000x reference)
//
#include <hip/hip_runtime.h>
#include <hip/hip_bf16.h>
#include <stdint.h>

#define BATCH   512
#define INCH    20
#define FEAT    128
#define KACT    16
#define NUNIT   12

typedef short bf16x8 __attribute__((ext_vector_type(8)));
typedef float f32x4  __attribute__((ext_vector_type(4)));
typedef float f32x16 __attribute__((ext_vector_type(16)));

// Wpack32: [ky][ks][h][f][8]  k = ks*16 + h*8 + j -> (kx=k/20, c=k%20), 0 for k>=60
#define WPACK_ELEMS (3*4*2*128*8)
// Whead:   [agent][kt][g][action][j], f = kt*32 + g*8 + j  (16x16x32 head, unchanged)
#define WHEAD_ELEMS (4*4*4*16*8)

#define XIN_ROWS  18                        // padded rows y0-1 .. y0+16
#define XIN_ELEMS (XIN_ROWS*34*20 + 64)     // + slack for k>=60 overreads (stays zero)

__device__ __forceinline__ uint16_t f2bf(float f) {
    union { float f; uint32_t u; } x{f};
    uint32_t u = x.u;
    return (uint16_t)((u + 0x7FFFu + ((u >> 16) & 1u)) >> 16);  // RNE
}

__device__ __forceinline__ uint32_t cvt_pk_bf16(float lo, float hi) {
    uint32_t r;
    asm("v_cvt_pk_bf16_f32 %0, %1, %2" : "=v"(r) : "v"(lo), "v"(hi));
    return r;
}

// lgkm-only barrier: only LDS ordering needed across the per-step barrier.
__device__ __forceinline__ void lds_barrier() {
    asm volatile("s_waitcnt lgkmcnt(0)\n\ts_barrier" ::: "memory");
}

// ---- One-time weight repack (fp32 -> bf16 fragment order) ----
__global__ void repack_kernel(const float* __restrict__ conv_w,
                              const float* __restrict__ W_all,
                              uint16_t* __restrict__ Wpack,
                              uint16_t* __restrict__ Whead) {
    int idx = blockIdx.x * 256 + threadIdx.x;
    if (idx < WPACK_ELEMS) {
        int j = idx & 7, t = idx >> 3;
        int f = t & 127; t >>= 7;
        int h = t & 1;   t >>= 1;
        int ks = t & 3;  int ky = t >> 2;
        int k = ks * 16 + h * 8 + j;
        float v = 0.0f;
        if (k < 60) {
            int kx = k / 20, c = k % 20;
            v = conv_w[((f * INCH + c) * 3 + ky) * 3 + kx];
        }
        Wpack[idx] = f2bf(v);
    } else if (idx < WPACK_ELEMS + WHEAD_ELEMS) {
        int i = idx - WPACK_ELEMS;
        int j = i & 7, t = i >> 3;
        int a = t & 15; t >>= 4;
        int g = t & 3;  t >>= 2;
        int kt = t & 3; int ag = t >> 2;
        int f = kt * 32 + g * 8 + j;
        Whead[i] = f2bf(W_all[(ag * KACT + a) * FEAT + f]);
    }
}

// ---- Fused conv3x3 + relu/bias/mask + per-sample head GEMM ----
// 32x32x16 conv MFMAs: wave = (feature-half fh, row-parity rp) in a 256-thread
// block; block = half a sample (16 rows); grid 1024, 2 blocks/CU (2 waves/SIMD,
// 256-reg budget). Each im2col b128 read feeds 2 N-tiles (64 feats) -> 2x less
// conv LDS traffic than R9. Head (16x16x32) + xl double buffer + lgkm-only
// barrier unchanged from R9.
__global__ __launch_bounds__(256, 2) void fused_mfma_kernel(
    const float* __restrict__ states,    // [512,20,32,32]
    const int*   __restrict__ labels,    // [512]
    const float* __restrict__ maskings,  // [512,1,32,32]
    const float* __restrict__ conv_b,    // [128]
    const float* __restrict__ b_all,     // [4,16]
    const uint16_t* __restrict__ Wpack,
    const uint16_t* __restrict__ Whead,
    float*       __restrict__ out)       // [512*1024*12] ++ [512*1024*4]
{
    __shared__ __align__(16) uint16_t xin[XIN_ELEMS];   // 24,608 B
    __shared__ __align__(16) uint16_t xl[2 * 64 * 128]; // 32,768 B [buf][pos][feat]

    const int bid  = blockIdx.x;
    const int b    = bid >> 1;
    const int y0   = (bid & 1) << 4;   // rows y0 .. y0+15
    const int tid  = threadIdx.x;
    const int lane = tid & 63;
    const int w    = tid >> 6;     // 0..3
    const int fh   = w >> 1;       // feature half: feats fh*64 .. +63
    const int rp   = w & 1;        // row parity within step
    const int l31  = lane & 31;
    const int h    = lane >> 5;    // 0..1
    const int l15  = lane & 15;
    const int g    = lane >> 4;    // 0..3 (head)

    // ---- zero xin ----
    for (int i = tid; i < (XIN_ELEMS * 2) / 16; i += 256)
        ((uint4*)xin)[i] = uint4{0, 0, 0, 0};
    __syncthreads();

    // ---- stage rows r=0..17 (global y = y0+r-1): fp32 -> xin[r][x+1][c] bf16 ----
    for (int t = 0; t < 12; ++t) {
        int i = t * 256 + tid;
        if (i < XIN_ROWS * 5 * 32) {
            int p  = i & 31;
            int tt = i >> 5;
            int cg = tt % 5;
            int r  = tt / 5;
            int y  = y0 + r - 1;
            if (y >= 0 && y < 32) {
                const float* sp = states + (size_t)b * (INCH * 1024) + cg * 4096 + y * 32 + p;
                float v0 = sp[0], v1 = sp[1024], v2 = sp[2048], v3 = sp[3072];
                uint64_t lo = cvt_pk_bf16(v0, v1);
                uint64_t hi = cvt_pk_bf16(v2, v3);
                *(uint64_t*)&xin[(r * 34 + p + 1) * 20 + cg * 4] = lo | (hi << 32);
            }
        }
    }

    // ---- per-lane invariants ----
    const int label = labels[b];

    // acc init = conv bias, in C/D layout: f = fh*64 + nt*32 + 8q + 4h + e
    f32x16 accI[2];
    #pragma unroll
    for (int nt = 0; nt < 2; ++nt)
        #pragma unroll
        for (int q = 0; q < 4; ++q) {
            f32x4 c4 = *(const f32x4*)&conv_b[fh * 64 + nt * 32 + q * 8 + h * 4];
            #pragma unroll
            for (int e = 0; e < 4; ++e) accI[nt][q * 4 + e] = c4[e];
        }

    const f32x4 hb = *(const f32x4*)&b_all[label * KACT + g * 4];  // actions g*4..+3
    bf16x8 Wh[4];                      // head A-frags: lane l15 = action, k = g*8+j
    #pragma unroll
    for (int kt = 0; kt < 4; ++kt)
        Wh[kt] = *(const bf16x8*)&Whead[(((label * 4 + kt) * 4 + g) * 16 + l15) * 8];

    // conv A-frags (weights), resident: [nt][ky][ks] = 24 frags = 96 VGPRs
    bf16x8 Wc[2][3][4];
    #pragma unroll
    for (int nt = 0; nt < 2; ++nt)
        #pragma unroll
        for (int ky = 0; ky < 3; ++ky)
            #pragma unroll
            for (int ks = 0; ks < 4; ++ks)
                Wc[nt][ky][ks] = *(const bf16x8*)
                    &Wpack[((((ky * 4 + ks) * 2 + h) * 128 + fh * 64 + nt * 32 + l31) * 8)];

    const int posx  = rp * 32 + l31;          // xl pos written by this lane
    const int wswz  = (posx & 7) << 4;        // write-side swizzle
    const int hoff0 = (w * 16 + l15) * 256;   // head read base (pos = w*16+l15)
    const int hswz  = (l15 & 7) << 4;         // read-side swizzle (pos&7 == l15&7)

    __syncthreads();  // xin fully staged

    // ---- 8 steps; step s: rows {2s, 2s+1} local; one lgkm-only barrier per step ----
    #pragma unroll 2
    for (int s = 0; s < 8; ++s) {
        const int lr = 2 * s + rp;            // local row this wave convolves

        const float m = maskings[(size_t)b * 1024 + (y0 + lr) * 32 + l31];

        f32x16 acc0 = accI[0];
        f32x16 acc1 = accI[1];

        // conv: B = im2col row (n = pos = l31, k = h*8+j), A = resident weights
        __builtin_amdgcn_s_setprio(1);
        #pragma unroll
        for (int ky = 0; ky < 3; ++ky) {
            const char* rbase = (const char*)xin + (((lr + ky) * 34 + l31) * 20 + h * 8) * 2;
            #pragma unroll
            for (int ks = 0; ks < 4; ++ks) {
                bf16x8 X = *(const bf16x8*)(rbase + ks * 32);
                acc0 = __builtin_amdgcn_mfma_f32_32x32x16_bf16(Wc[0][ky][ks], X, acc0, 0, 0, 0);
                acc1 = __builtin_amdgcn_mfma_f32_32x32x16_bf16(Wc[1][ky][ks], X, acc1, 0, 0, 0);
            }
        }
        __builtin_amdgcn_s_setprio(0);

        // epilogue: relu + mask (bias already in acc), pack bf16, swizzled xl write
        char* xbase = (char*)xl + (s & 1) * 16384;
        #pragma unroll
        for (int nt = 0; nt < 2; ++nt) {
            const f32x16 A = nt ? acc1 : acc0;
            #pragma unroll
            for (int q = 0; q < 4; ++q) {
                float x0 = fmaxf(A[q * 4 + 0], 0.f) * m;
                float x1 = fmaxf(A[q * 4 + 1], 0.f) * m;
                float x2 = fmaxf(A[q * 4 + 2], 0.f) * m;
                float x3 = fmaxf(A[q * 4 + 3], 0.f) * m;
                uint64_t pk = (uint64_t)cvt_pk_bf16(x0, x1)
                            | ((uint64_t)cvt_pk_bf16(x2, x3) << 32);
                const int off = posx * 256 + fh * 128 + nt * 64 + q * 16 + h * 8;
                *(uint64_t*)(xbase + (off ^ wswz)) = pk;
            }
        }

        lds_barrier();  // xl[s&1] complete; out-stores stay in flight

        // head: all 4 waves, tile w: pos = w*16+l15, K=128 = 4 kt slices
        {
            f32x4 hacc = f32x4{0.f, 0.f, 0.f, 0.f};
            __builtin_amdgcn_s_setprio(1);
            #pragma unroll
            for (int kt = 0; kt < 4; ++kt) {
                const int off = hoff0 + kt * 64 + g * 16;
                bf16x8 bx = *(const bf16x8*)(xbase + (off ^ hswz));
                hacc = __builtin_amdgcn_mfma_f32_16x16x32_bf16(Wh[kt], bx, hacc, 0, 0, 0);
            }
            __builtin_amdgcn_s_setprio(0);
            const int y = y0 + 2 * s + (w >> 1);
            const size_t pos = (size_t)b * 1024 + y * 32 + (w & 1) * 16 + l15;
            f32x4 o = hacc + hb;
            if (g < 3) *(f32x4*)&out[pos * NUNIT + g * 4] = o;                    // actions 0..11
            else       *(f32x4*)&out[(size_t)BATCH * 1024 * NUNIT + pos * 4] = o; // actions 12..15
        }
    }
}

extern "C" void kernel_launch(void* const* d_in, const int* in_sizes, int n_in,
                              void* d_out, int out_size, void* d_ws, size_t ws_size,
                              hipStream_t stream) {
    const float* states   = (const float*)d_in[0];
    const int*   labels   = (const int*)d_in[1];
    const float* maskings = (const float*)d_in[2];
    const float* conv_w   = (const float*)d_in[3];
    const float* conv_b   = (const float*)d_in[4];
    const float* W_all    = (const float*)d_in[5];
    const float* b_all    = (const float*)d_in[6];
    float* out = (float*)d_out;

    uint16_t* Wpack = (uint16_t*)d_ws;
    uint16_t* Whead = Wpack + WPACK_ELEMS;

    repack_kernel<<<(WPACK_ELEMS + WHEAD_ELEMS + 255) / 256, 256, 0, stream>>>(
        conv_w, W_all, Wpack, Whead);
    fused_mfma_kernel<<<BATCH * 2, 256, 0, stream>>>(
        states, labels, maskings, conv_b, b_all, Wpack, Whead, out);
}

// Round 13
// 54.399 us; speedup vs baseline: 1.3341x; 1.3341x over previous
//
#include <hip/hip_runtime.h>
#include <hip/hip_bf16.h>
#include <stdint.h>

#define BATCH   512
#define INCH    20
#define FEAT    128
#define KACT    16
#define NUNIT   12

typedef short bf16x8 __attribute__((ext_vector_type(8)));
typedef float f32x4  __attribute__((ext_vector_type(4)));

#define BPACK_ELEMS (3*2*4*128*8)   // [ky][kk][g][f][j], k = kk*32+g*8+j -> (kx=k/20, c=k%20), 0 for k>=60
#define WHEAD_ELEMS (4*4*4*16*8)    // [agent][kt][g][action][j], f = kt*32+g*8+j

#define XIN_ROWS  10                       // padded rows y0-1 .. y0+8
#define XIN_ELEMS (XIN_ROWS*34*20 + 64)    // 6864 elems; slack for k>=60 overreads (stays zero / harmless)

__device__ __forceinline__ uint16_t f2bf(float f) {
    union { float f; uint32_t u; } x{f};
    uint32_t u = x.u;
    return (uint16_t)((u + 0x7FFFu + ((u >> 16) & 1u)) >> 16);  // RNE
}

__device__ __forceinline__ uint32_t cvt_pk_bf16(float lo, float hi) {
    uint32_t r;
    asm("v_cvt_pk_bf16_f32 %0, %1, %2" : "=v"(r) : "v"(lo), "v"(hi));
    return r;
}

// lgkm-only barrier: only LDS ordering needed across the per-step barrier.
__device__ __forceinline__ void lds_barrier() {
    asm volatile("s_waitcnt lgkmcnt(0)\n\ts_barrier" ::: "memory");
}

// ---- One-time weight repack (fp32 -> bf16 fragment order) ---- (unchanged)
__global__ void repack_kernel(const float* __restrict__ conv_w,
                              const float* __restrict__ W_all,
                              uint16_t* __restrict__ Bpack,
                              uint16_t* __restrict__ Whead) {
    int idx = blockIdx.x * 256 + threadIdx.x;
    if (idx < BPACK_ELEMS) {
        int j = idx & 7, t = idx >> 3;
        int f = t & 127; t >>= 7;
        int g = t & 3;   t >>= 2;
        int kk = t & 1;  int ky = t >> 1;
        int k = kk * 32 + g * 8 + j;
        float v = 0.0f;
        if (k < 60) {
            int kx = k / 20, c = k % 20;
            v = conv_w[((f * INCH + c) * 3 + ky) * 3 + kx];
        }
        Bpack[idx] = f2bf(v);
    } else if (idx < BPACK_ELEMS + WHEAD_ELEMS) {
        int i = idx - BPACK_ELEMS;
        int j = i & 7, t = i >> 3;
        int a = t & 15; t >>= 4;
        int g = t & 3;  t >>= 2;
        int kt = t & 3; int ag = t >> 2;
        int f = kt * 32 + g * 8 + j;
        Whead[i] = f2bf(W_all[(ag * KACT + a) * FEAT + f]);
    }
}

// ---- Fused conv3x3 + relu/bias/mask + per-sample head GEMM ----
// Quarter-sample blocks: 2048 blocks x 256 thr (4 waves = 2 row-parity x 2
// feature-HALVES). LDS ~51 KB -> 3 blocks/CU, launch_bounds(256,3): each SIMD
// hosts 3 waves from 3 INDEPENDENT blocks (de-phased barrier groups — the
// R6/R9/R12 scaling says lockstep coupling, not resources, is the wall).
// Feature-halves also halve conv LDS reads. acc processed per-ptile
// sequentially (16 regs) + Wh staged in LDS to fit the 170-reg cap.
__global__ __launch_bounds__(256, 3) void fused_mfma_kernel(
    const float* __restrict__ states,    // [512,20,32,32]
    const int*   __restrict__ labels,    // [512]
    const float* __restrict__ maskings,  // [512,1,32,32]
    const float* __restrict__ conv_b,    // [128]
    const float* __restrict__ b_all,     // [4,16]
    const uint16_t* __restrict__ Bpack,
    const uint16_t* __restrict__ Whead,
    float*       __restrict__ out)       // [512*1024*12] ++ [512*1024*4]
{
    __shared__ __align__(16) uint16_t xin[XIN_ELEMS];    // 13,728 B
    __shared__ __align__(16) uint16_t xl[2 * 64 * 128];  // 32,768 B
    __shared__ __align__(16) uint16_t whl[4 * 4 * 16 * 8]; // 4,096 B (label's head frags)

    const int bid  = blockIdx.x;
    const int b    = bid >> 2;
    const int y0   = (bid & 3) << 3;   // rows y0 .. y0+7
    const int tid  = threadIdx.x;
    const int lane = tid & 63;
    const int w    = tid >> 6;     // 0..3
    const int wr   = w & 1;        // row parity within step
    const int fh   = w >> 1;       // feature half: feats fh*64 .. +63
    const int l15  = lane & 15;
    const int g    = lane >> 4;    // 0..3
    const int swz  = (l15 & 7) << 4;

    // ---- zero xin ----
    for (int i = tid; i < (XIN_ELEMS * 2) / 16; i += 256)
        ((uint4*)xin)[i] = uint4{0, 0, 0, 0};
    __syncthreads();

    const int label = labels[b];

    // ---- stage xin rows r=0..9 (global y = y0+r-1) + whl ----
    for (int t = 0; t < 7; ++t) {
        int i = t * 256 + tid;
        if (i < XIN_ROWS * 5 * 32) {
            int p  = i & 31;
            int tt = i >> 5;
            int cg = tt % 5;
            int r  = tt / 5;
            int y  = y0 + r - 1;
            if (y >= 0 && y < 32) {
                const float* sp = states + (size_t)b * (INCH * 1024) + cg * 4096 + y * 32 + p;
                float v0 = sp[0], v1 = sp[1024], v2 = sp[2048], v3 = sp[3072];
                uint64_t lo = cvt_pk_bf16(v0, v1);
                uint64_t hi = cvt_pk_bf16(v2, v3);
                *(uint64_t*)&xin[(r * 34 + p + 1) * 20 + cg * 4] = lo | (hi << 32);
            }
        }
    }
    // whl[i*8..] = Whead[label][kt][g][a][*], i = (kt*4+g)*16 + a
    {
        *(bf16x8*)&whl[tid * 8] = *(const bf16x8*)&Whead[(label * 256 + tid) * 8];
    }

    // ---- per-lane invariants (registers) ----
    f32x4 cb[4];                       // conv bias: f = fh*64 + nt*16 + g*4 + j
    #pragma unroll
    for (int nt = 0; nt < 4; ++nt)
        cb[nt] = *(const f32x4*)&conv_b[fh * 64 + nt * 16 + g * 4];
    const f32x4 hb = *(const f32x4*)&b_all[label * KACT + g * 4];

    // conv A-frags for this wave's feature half: 24 frags = 96 VGPRs
    bf16x8 Wc[3][2][4];
    #pragma unroll
    for (int ky = 0; ky < 3; ++ky)
        #pragma unroll
        for (int kk = 0; kk < 2; ++kk)
            #pragma unroll
            for (int nt = 0; nt < 4; ++nt)
                Wc[ky][kk][nt] = *(const bf16x8*)
                    &Bpack[((((ky * 2 + kk) * 4 + g) * 128 + fh * 64 + nt * 16 + l15) * 8)];

    const int hoff0 = (w * 16 + l15) * 256;  // head read byte base (pos = w*16+l15)

    __syncthreads();  // xin + whl staged

    // ---- 4 steps; step s: rows {y0+2s, y0+2s+1}; one lgkm barrier per step ----
    #pragma unroll 2
    for (int s = 0; s < 4; ++s) {
        const int lr = 2 * s + wr;          // local row this wave convolves
        const int y  = y0 + lr;

        const float m0 = maskings[(size_t)b * 1024 + y * 32 + l15];
        const float m1 = maskings[(size_t)b * 1024 + y * 32 + 16 + l15];

        char* xbase = (char*)xl + (s & 1) * 16384;

        // ptiles processed sequentially (halves acc registers: 16 live)
        __builtin_amdgcn_s_setprio(1);
        #pragma unroll
        for (int pt = 0; pt < 2; ++pt) {
            f32x4 acc[4];
            #pragma unroll
            for (int nt = 0; nt < 4; ++nt) acc[nt] = f32x4{0.f, 0.f, 0.f, 0.f};

            #pragma unroll
            for (int ky = 0; ky < 3; ++ky) {
                const uint64_t* ap = (const uint64_t*)
                    &xin[((lr + ky) * 34 + pt * 16 + l15) * 20 + g * 8];
                #pragma unroll
                for (int kk = 0; kk < 2; ++kk) {
                    union { uint64_t u[2]; bf16x8 v; } B;
                    B.u[0] = ap[kk * 8 + 0];
                    B.u[1] = ap[kk * 8 + 1];
                    #pragma unroll
                    for (int nt = 0; nt < 4; ++nt)
                        acc[nt] = __builtin_amdgcn_mfma_f32_16x16x32_bf16(
                            Wc[ky][kk][nt], B.v, acc[nt], 0, 0, 0);
                }
            }

            // epilogue for this ptile: bias+relu+mask, pack, swizzled xl write
            const float m = pt ? m1 : m0;
            #pragma unroll
            for (int nt = 0; nt < 4; ++nt) {
                float x0 = fmaxf(acc[nt][0] + cb[nt][0], 0.f) * m;
                float x1 = fmaxf(acc[nt][1] + cb[nt][1], 0.f) * m;
                float x2 = fmaxf(acc[nt][2] + cb[nt][2], 0.f) * m;
                float x3 = fmaxf(acc[nt][3] + cb[nt][3], 0.f) * m;
                uint64_t pk = (uint64_t)cvt_pk_bf16(x0, x1)
                            | ((uint64_t)cvt_pk_bf16(x2, x3) << 32);
                // pos p = wr*32 + pt*16 + l15 ; feat byte = fh*128 + nt*32 + g*8
                const int off = ((wr * 2 + pt) * 16 + l15) * 256 + fh * 128 + nt * 32 + g * 8;
                *(uint64_t*)(xbase + (off ^ swz)) = pk;
            }
        }
        __builtin_amdgcn_s_setprio(0);

        lds_barrier();  // xl[s&1] complete; out-stores stay in flight

        // head: wave w -> tile w (pos = w*16+l15); K=128 = 4 kt; Wh from LDS
        {
            f32x4 h0 = f32x4{0.f, 0.f, 0.f, 0.f};
            f32x4 h1 = f32x4{0.f, 0.f, 0.f, 0.f};
            __builtin_amdgcn_s_setprio(1);
            #pragma unroll
            for (int kt = 0; kt < 4; ++kt) {
                bf16x8 wh = *(const bf16x8*)&whl[((kt * 4 + g) * 16 + l15) * 8];
                const int off = hoff0 + kt * 64 + g * 16;
                bf16x8 bx = *(const bf16x8*)(xbase + (off ^ swz));
                if (kt & 1) h1 = __builtin_amdgcn_mfma_f32_16x16x32_bf16(wh, bx, h1, 0, 0, 0);
                else        h0 = __builtin_amdgcn_mfma_f32_16x16x32_bf16(wh, bx, h0, 0, 0, 0);
            }
            __builtin_amdgcn_s_setprio(0);
            const int hy = y0 + 2 * s + (w >> 1);
            const size_t pos = (size_t)b * 1024 + hy * 32 + (w & 1) * 16 + l15;
            f32x4 o = h0 + h1 + hb;
            if (g < 3) *(f32x4*)&out[pos * NUNIT + g * 4] = o;                    // actions 0..11
            else       *(f32x4*)&out[(size_t)BATCH * 1024 * NUNIT + pos * 4] = o; // actions 12..15
        }
    }
}

extern "C" void kernel_launch(void* const* d_in, const int* in_sizes, int n_in,
                              void* d_out, int out_size, void* d_ws, size_t ws_size,
                              hipStream_t stream) {
    const float* states   = (const float*)d_in[0];
    const int*   labels   = (const int*)d_in[1];
    const float* maskings = (const float*)d_in[2];
    const float* conv_w   = (const float*)d_in[3];
    const float* conv_b   = (const float*)d_in[4];
    const float* W_all    = (const float*)d_in[5];
    const float* b_all    = (const float*)d_in[6];
    float* out = (float*)d_out;

    uint16_t* Bpack = (uint16_t*)d_ws;
    uint16_t* Whead = Bpack + BPACK_ELEMS;

    repack_kernel<<<(BPACK_ELEMS + WHEAD_ELEMS + 255) / 256, 256, 0, stream>>>(
        conv_w, W_all, Bpack, Whead);
    fused_mfma_kernel<<<BATCH * 4, 256, 0, stream>>>(
        states, labels, maskings, conv_b, b_all, Bpack, Whead, out);
}

// Round 14
// 42.153 us; speedup vs baseline: 1.7217x; 1.2905x over previous
//
#include <hip/hip_runtime.h>
#include <hip/hip_bf16.h>
#include <stdint.h>

#define BATCH   512
#define INCH    20
#define FEAT    128
#define KACT    16
#define NUNIT   12

typedef short bf16x8 __attribute__((ext_vector_type(8)));
typedef float f32x4  __attribute__((ext_vector_type(4)));

#define BPACK_ELEMS (3*2*4*128*8)   // [ky][kk][g][f][j], k = kk*32+g*8+j -> (kx=k/20, c=k%20), 0 for k>=60
#define WHEAD_ELEMS (4*4*4*16*8)    // [agent][kt][g][action][j], f = kt*32+g*8+j

#define XIN_ROWS  10                       // padded rows y0-1 .. y0+8
#define XIN_ELEMS (XIN_ROWS*34*20 + 64)    // + slack for k>=60 overreads (stays zero)

__device__ __forceinline__ uint16_t f2bf(float f) {
    union { float f; uint32_t u; } x{f};
    uint32_t u = x.u;
    return (uint16_t)((u + 0x7FFFu + ((u >> 16) & 1u)) >> 16);  // RNE
}

__device__ __forceinline__ uint32_t cvt_pk_bf16(float lo, float hi) {
    uint32_t r;
    asm("v_cvt_pk_bf16_f32 %0, %1, %2" : "=v"(r) : "v"(lo), "v"(hi));
    return r;
}

// lgkm-only barrier: only LDS ordering needed across the per-step barrier.
__device__ __forceinline__ void lds_barrier() {
    asm volatile("s_waitcnt lgkmcnt(0)\n\ts_barrier" ::: "memory");
}

// ---- One-time weight repack (fp32 -> bf16 fragment order) ---- (unchanged)
__global__ void repack_kernel(const float* __restrict__ conv_w,
                              const float* __restrict__ W_all,
                              uint16_t* __restrict__ Bpack,
                              uint16_t* __restrict__ Whead) {
    int idx = blockIdx.x * 256 + threadIdx.x;
    if (idx < BPACK_ELEMS) {
        int j = idx & 7, t = idx >> 3;
        int f = t & 127; t >>= 7;
        int g = t & 3;   t >>= 2;
        int kk = t & 1;  int ky = t >> 1;
        int k = kk * 32 + g * 8 + j;
        float v = 0.0f;
        if (k < 60) {
            int kx = k / 20, c = k % 20;
            v = conv_w[((f * INCH + c) * 3 + ky) * 3 + kx];
        }
        Bpack[idx] = f2bf(v);
    } else if (idx < BPACK_ELEMS + WHEAD_ELEMS) {
        int i = idx - BPACK_ELEMS;
        int j = i & 7, t = i >> 3;
        int a = t & 15; t >>= 4;
        int g = t & 3;  t >>= 2;
        int kt = t & 3; int ag = t >> 2;
        int f = kt * 32 + g * 8 + j;
        Whead[i] = f2bf(W_all[(ag * KACT + a) * FEAT + f]);
    }
}

// ---- Fused conv3x3 + relu/bias/mask + per-sample head GEMM ----
// De-phased quarter-sample blocks: 2048 blocks x 256 thr = 4 waves, ALL with
// R9's per-wave budget (F=32, Wc=48 regs -> no spill at the 128-reg cap).
// One row per step; LDS ~30 KB -> 4 independent blocks/CU: 16 waves/CU (same
// as R9) but 4 de-phased barrier groups per SIMD instead of 2, each barrier
// coupling 4 waves (one per SIMD) instead of 8. Clean A/B on the lockstep
// theory (R6/R9/R12/R13 scaling curve).
__global__ __launch_bounds__(256, 4) void fused_mfma_kernel(
    const float* __restrict__ states,    // [512,20,32,32]
    const int*   __restrict__ labels,    // [512]
    const float* __restrict__ maskings,  // [512,1,32,32]
    const float* __restrict__ conv_b,    // [128]
    const float* __restrict__ b_all,     // [4,16]
    const uint16_t* __restrict__ Bpack,
    const uint16_t* __restrict__ Whead,
    float*       __restrict__ out)       // [512*1024*12] ++ [512*1024*4]
{
    __shared__ __align__(16) uint16_t xin[XIN_ELEMS];    // 13,728 B
    __shared__ __align__(16) uint16_t xl[2 * 32 * 128];  // 16,384 B [buf][pos][feat]

    const int bid  = blockIdx.x;
    const int b    = bid >> 2;
    const int y0   = (bid & 3) << 3;   // rows y0 .. y0+7
    const int tid  = threadIdx.x;
    const int lane = tid & 63;
    const int fq   = tid >> 6;     // 0..3 : feature quarter (feats fq*32..+31)
    const int l15  = lane & 15;
    const int g    = lane >> 4;    // 0..3
    const int swz  = (l15 & 7) << 4;   // XOR swizzle (pos&7 == l15&7 on both sides)

    // ---- zero xin ----
    for (int i = tid; i < (XIN_ELEMS * 2) / 16; i += 256)
        ((uint4*)xin)[i] = uint4{0, 0, 0, 0};
    __syncthreads();

    // ---- stage xin rows r=0..9 (global y = y0+r-1) ----
    for (int t = 0; t < 7; ++t) {
        int i = t * 256 + tid;
        if (i < XIN_ROWS * 5 * 32) {
            int p  = i & 31;
            int tt = i >> 5;
            int cg = tt % 5;
            int r  = tt / 5;
            int y  = y0 + r - 1;
            if (y >= 0 && y < 32) {
                const float* sp = states + (size_t)b * (INCH * 1024) + cg * 4096 + y * 32 + p;
                float v0 = sp[0], v1 = sp[1024], v2 = sp[2048], v3 = sp[3072];
                uint64_t lo = cvt_pk_bf16(v0, v1);
                uint64_t hi = cvt_pk_bf16(v2, v3);
                *(uint64_t*)&xin[(r * 34 + p + 1) * 20 + cg * 4] = lo | (hi << 32);
            }
        }
    }

    // ---- per-lane invariants (R9's exact budget) ----
    const int label = labels[b];
    f32x4 cb[2];                       // conv bias: f = fq*32 + nt*16 + g*4 + j
    #pragma unroll
    for (int nt = 0; nt < 2; ++nt)
        cb[nt] = *(const f32x4*)&conv_b[fq * 32 + nt * 16 + g * 4];
    const f32x4 hb = *(const f32x4*)&b_all[label * KACT + g * 4];  // actions g*4..+3
    bf16x8 Wh[4];                      // head A-frags: lane l15 = action, k = g*8+j
    #pragma unroll
    for (int kt = 0; kt < 4; ++kt)
        Wh[kt] = *(const bf16x8*)&Whead[(((label * 4 + kt) * 4 + g) * 16 + l15) * 8];

    // conv A-frags for this wave's feature quarter: 12 frags = 48 VGPRs
    bf16x8 Wc[3][2][2];
    #pragma unroll
    for (int ky = 0; ky < 3; ++ky)
        #pragma unroll
        for (int kk = 0; kk < 2; ++kk)
            #pragma unroll
            for (int nt = 0; nt < 2; ++nt)
                Wc[ky][kk][nt] = *(const bf16x8*)
                    &Bpack[((((ky * 2 + kk) * 4 + g) * 128 + fq * 32 + nt * 16 + l15) * 8)];

    const int hoff0 = (fq * 16 + l15) * 256;  // head read byte base (pos = fq*16+l15)
    const bool do_head = (fq < 2);

    __syncthreads();  // xin fully staged

    // ---- 8 steps; step s: row y = y0+s; one lgkm-only barrier per step ----
    #pragma unroll 2
    for (int s = 0; s < 8; ++s) {
        const int y = y0 + s;

        // masks (issue early; consumed in epilogue)
        const float m0 = maskings[(size_t)b * 1024 + y * 32 + l15];
        const float m1 = maskings[(size_t)b * 1024 + y * 32 + 16 + l15];

        f32x4 acc[2][2];   // [ptile][nt] : D[f = fq*32+nt*16+g*4+j][p = pt*16+l15]
        #pragma unroll
        for (int pt = 0; pt < 2; ++pt)
            #pragma unroll
            for (int nt = 0; nt < 2; ++nt)
                acc[pt][nt] = f32x4{0.f, 0.f, 0.f, 0.f};

        // conv: A = resident quarter-weights, B = im2col rows from xin
        __builtin_amdgcn_s_setprio(1);
        #pragma unroll
        for (int ky = 0; ky < 3; ++ky) {
            const uint64_t* a0 = (const uint64_t*)&xin[((s + ky) * 34 + l15) * 20 + g * 8];
            const uint64_t* a1 = (const uint64_t*)&xin[((s + ky) * 34 + 16 + l15) * 20 + g * 8];
            #pragma unroll
            for (int kk = 0; kk < 2; ++kk) {
                union { uint64_t u[2]; bf16x8 v; } B0, B1;
                B0.u[0] = a0[kk * 8 + 0]; B0.u[1] = a0[kk * 8 + 1];
                B1.u[0] = a1[kk * 8 + 0]; B1.u[1] = a1[kk * 8 + 1];
                #pragma unroll
                for (int nt = 0; nt < 2; ++nt) {
                    acc[0][nt] = __builtin_amdgcn_mfma_f32_16x16x32_bf16(
                        Wc[ky][kk][nt], B0.v, acc[0][nt], 0, 0, 0);
                    acc[1][nt] = __builtin_amdgcn_mfma_f32_16x16x32_bf16(
                        Wc[ky][kk][nt], B1.v, acc[1][nt], 0, 0, 0);
                }
            }
        }
        __builtin_amdgcn_s_setprio(0);

        // epilogue: bias+relu+mask, pack bf16, swizzled write into xl[s&1]
        char* xbase = (char*)xl + (s & 1) * 8192;
        #pragma unroll
        for (int pt = 0; pt < 2; ++pt) {
            const float m = pt ? m1 : m0;
            #pragma unroll
            for (int nt = 0; nt < 2; ++nt) {
                float x0 = fmaxf(acc[pt][nt][0] + cb[nt][0], 0.f) * m;
                float x1 = fmaxf(acc[pt][nt][1] + cb[nt][1], 0.f) * m;
                float x2 = fmaxf(acc[pt][nt][2] + cb[nt][2], 0.f) * m;
                float x3 = fmaxf(acc[pt][nt][3] + cb[nt][3], 0.f) * m;
                uint64_t pk = (uint64_t)cvt_pk_bf16(x0, x1)
                            | ((uint64_t)cvt_pk_bf16(x2, x3) << 32);
                // pos = pt*16 + l15 ; feat byte = fq*64 + nt*32 + g*8
                const int off = (pt * 16 + l15) * 256 + fq * 64 + nt * 32 + g * 8;
                *(uint64_t*)(xbase + (off ^ swz)) = pk;
            }
        }

        lds_barrier();  // xl[s&1] complete; out-stores stay in flight

        // head: waves fq<2 do tile fq (pos = fq*16+l15); K=128 = 4 kt slices
        if (do_head) {
            f32x4 hacc = f32x4{0.f, 0.f, 0.f, 0.f};
            __builtin_amdgcn_s_setprio(1);
            #pragma unroll
            for (int kt = 0; kt < 4; ++kt) {
                const int off = hoff0 + kt * 64 + g * 16;
                bf16x8 bx = *(const bf16x8*)(xbase + (off ^ swz));
                hacc = __builtin_amdgcn_mfma_f32_16x16x32_bf16(Wh[kt], bx, hacc, 0, 0, 0);
            }
            __builtin_amdgcn_s_setprio(0);
            const size_t pos = (size_t)b * 1024 + y * 32 + fq * 16 + l15;
            f32x4 o = hacc + hb;
            if (g < 3) *(f32x4*)&out[pos * NUNIT + g * 4] = o;                    // actions 0..11
            else       *(f32x4*)&out[(size_t)BATCH * 1024 * NUNIT + pos * 4] = o; // actions 12..15
        }
    }
}

extern "C" void kernel_launch(void* const* d_in, const int* in_sizes, int n_in,
                              void* d_out, int out_size, void* d_ws, size_t ws_size,
                              hipStream_t stream) {
    const float* states   = (const float*)d_in[0];
    const int*   labels   = (const int*)d_in[1];
    const float* maskings = (const float*)d_in[2];
    const float* conv_w   = (const float*)d_in[3];
    const float* conv_b   = (const float*)d_in[4];
    const float* W_all    = (const float*)d_in[5];
    const float* b_all    = (const float*)d_in[6];
    float* out = (float*)d_out;

    uint16_t* Bpack = (uint16_t*)d_ws;
    uint16_t* Whead = Bpack + BPACK_ELEMS;

    repack_kernel<<<(BPACK_ELEMS + WHEAD_ELEMS + 255) / 256, 256, 0, stream>>>(
        conv_w, W_all, Bpack, Whead);
    fused_mfma_kernel<<<BATCH * 4, 256, 0, stream>>>(
        states, labels, maskings, conv_b, b_all, Bpack, Whead, out);
}